// Round 5
// baseline (110.092 us; speedup 1.0000x reference)
//
#include <hip/hip_runtime.h>

// out[r][c] = (float)weight[r][c] * scale[r]
// weight: int32 container holding int8 values, shape (8192, 8192)
// scale:  f32, shape (8192, 1)
// out:    f32, shape (8192, 8192)
//
// Memory-bound streaming: 256 MB read + 256 MB write, zero reuse.
// R2: grid-stride 4x unroll + nt  -> 116 us (REGRESS: 8 MB inter-load stride)
// R3: block-interleaved 16KB chunks -> 99.8 us (5.13 TB/s)
// R4: per-block CONTIGUOUS 128 KB span (one sequential stream per block,
//     no 32 MB chunk jumps) + 8x unroll (32 KB per iteration).

typedef int   iv4 __attribute__((ext_vector_type(4)));
typedef float fv4 __attribute__((ext_vector_type(4)));

#define BLOCK 256
#define UNROLL 8
#define CHUNK (BLOCK * UNROLL)   // 4-wide groups per block-iteration (= 32 KB)

__global__ __launch_bounds__(BLOCK) void decompress_int8_sym_kernel(
    const iv4* __restrict__ w4,
    const float* __restrict__ scale,
    fv4* __restrict__ out4,
    int n4,           // total 4-wide groups = OUT*IN/4
    int span,         // groups per block (multiple of CHUNK except last block)
    int row_shift)    // log2(IN/4)
{
    const int tid = threadIdx.x;
    long long start = (long long)blockIdx.x * span;
    long long end = start + span;
    if (end > n4) end = n4;

    long long base = start;
    // Full 8x-unrolled chunks, fully sequential per block
    for (; base + CHUNK <= end; base += CHUNK) {
        iv4 v[UNROLL];
        float s[UNROLL];
        int idx[UNROLL];
#pragma unroll
        for (int u = 0; u < UNROLL; ++u) {
            idx[u] = (int)base + u * BLOCK + tid;
            v[u] = w4[idx[u]];
        }
#pragma unroll
        for (int u = 0; u < UNROLL; ++u)
            s[u] = scale[idx[u] >> row_shift];
#pragma unroll
        for (int u = 0; u < UNROLL; ++u) {
            fv4 o;
            o.x = (float)v[u].x * s[u];
            o.y = (float)v[u].y * s[u];
            o.z = (float)v[u].z * s[u];
            o.w = (float)v[u].w * s[u];
            out4[idx[u]] = o;
        }
    }
    // Remainder within this block's span
    for (long long i = base + tid; i < end; i += BLOCK) {
        iv4 v = w4[i];
        float s = scale[(int)(i >> row_shift)];
        fv4 o;
        o.x = (float)v.x * s;
        o.y = (float)v.y * s;
        o.z = (float)v.z * s;
        o.w = (float)v.w * s;
        out4[i] = o;
    }
}

extern "C" void kernel_launch(void* const* d_in, const int* in_sizes, int n_in,
                              void* d_out, int out_size, void* d_ws, size_t ws_size,
                              hipStream_t stream) {
    const iv4* w4 = (const iv4*)d_in[0];         // int32 weights, vectorized x4
    const float* scale = (const float*)d_in[1];  // per-row scales
    fv4* out4 = (fv4*)d_out;

    const int n_weights = in_sizes[0];           // OUT * IN
    const int n_rows    = in_sizes[1];           // OUT
    const int in_per_row = n_weights / n_rows;   // IN
    const int groups_per_row = in_per_row / 4;   // IN/4 (power of two here)
    const int row_shift = __builtin_ctz(groups_per_row);
    const int n4 = n_weights / 4;

    const int grid = 2048;                       // 256 CU x 8 blocks = full occupancy
    // Contiguous span per block, rounded up to CHUNK
    int span = (n4 + grid - 1) / grid;
    span = (span + CHUNK - 1) / CHUNK * CHUNK;
    int nblocks = (n4 + span - 1) / span;        // may be < grid if n4 small

    decompress_int8_sym_kernel<<<nblocks, BLOCK, 0, stream>>>(w4, scale, out4, n4, span, row_shift);
}

// Round 6
// 105.257 us; speedup vs baseline: 1.0459x; 1.0459x over previous
//
#include <hip/hip_runtime.h>

// out[r][c] = (float)weight[r][c] * scale[r]
// weight: int32 container holding int8 values, shape (8192, 8192)
// scale:  f32, shape (8192, 1)
// out:    f32, shape (8192, 8192)
//
// Memory-bound streaming: 256 MB read + 256 MB write, zero reuse.
// History:
//  R1 simple grid-stride x4 vec          : 109.4 us (4.9 TB/s)
//  R2 grid-stride 4x unroll + nt         : 116.3 us (REGRESS: 8MB inter-load stride)
//  R3 block-interleaved 16KB chunks, x4  :  99.8 us (5.4 TB/s)  <- best
//  R4 per-block contiguous 128KB span,x8 : 110.1 us (REGRESS: lost grid-lockstep
//       sequential sweep; instantaneous footprint spread over full 256MB)
//  R5 = R3 + single change: UNROLL 4->8 (32KB chunks, longer read/write bursts
//       per wave to amortize DRAM bus turnaround; sweep property preserved)

typedef int   iv4 __attribute__((ext_vector_type(4)));
typedef float fv4 __attribute__((ext_vector_type(4)));

#define BLOCK 256
#define UNROLL 8
#define CHUNK (BLOCK * UNROLL)   // 4-wide groups per block-iteration (= 32 KB)

__global__ __launch_bounds__(BLOCK) void decompress_int8_sym_kernel(
    const iv4* __restrict__ w4,
    const float* __restrict__ scale,
    fv4* __restrict__ out4,
    int n4,           // total 4-wide groups = OUT*IN/4
    int row_shift)    // log2(IN/4)
{
    const int tid = threadIdx.x;
    const int nfull = n4 / CHUNK;            // number of full chunks

    // Full chunks: grid-lockstep sequential sweep, 8x unrolled bursts
    for (int c = blockIdx.x; c < nfull; c += gridDim.x) {
        int base = c * CHUNK;
        int idx[UNROLL];
        iv4 v[UNROLL];
        float s[UNROLL];
#pragma unroll
        for (int u = 0; u < UNROLL; ++u) {
            idx[u] = base + u * BLOCK + tid;
            v[u] = w4[idx[u]];
        }
#pragma unroll
        for (int u = 0; u < UNROLL; ++u)
            s[u] = scale[idx[u] >> row_shift];
#pragma unroll
        for (int u = 0; u < UNROLL; ++u) {
            fv4 o;
            o.x = (float)v[u].x * s[u];
            o.y = (float)v[u].y * s[u];
            o.z = (float)v[u].z * s[u];
            o.w = (float)v[u].w * s[u];
            out4[idx[u]] = o;
        }
    }

    // Tail (n4 % CHUNK groups) -- handled by block 0
    if (blockIdx.x == 0) {
        for (int i = nfull * CHUNK + tid; i < n4; i += BLOCK) {
            iv4 v = w4[i];
            float s = scale[i >> row_shift];
            fv4 o;
            o.x = (float)v.x * s;
            o.y = (float)v.y * s;
            o.z = (float)v.z * s;
            o.w = (float)v.w * s;
            out4[i] = o;
        }
    }
}

extern "C" void kernel_launch(void* const* d_in, const int* in_sizes, int n_in,
                              void* d_out, int out_size, void* d_ws, size_t ws_size,
                              hipStream_t stream) {
    const iv4* w4 = (const iv4*)d_in[0];         // int32 weights, vectorized x4
    const float* scale = (const float*)d_in[1];  // per-row scales
    fv4* out4 = (fv4*)d_out;

    const int n_weights = in_sizes[0];           // OUT * IN
    const int n_rows    = in_sizes[1];           // OUT
    const int in_per_row = n_weights / n_rows;   // IN
    const int groups_per_row = in_per_row / 4;   // IN/4 (power of two here)
    const int row_shift = __builtin_ctz(groups_per_row);
    const int n4 = n_weights / 4;

    int grid = (n4 + CHUNK - 1) / CHUNK;
    const int max_grid = 2048;                   // 256 CU x 8 blocks = full occupancy
    if (grid > max_grid) grid = max_grid;

    decompress_int8_sym_kernel<<<grid, BLOCK, 0, stream>>>(w4, scale, out4, n4, row_shift);
}

// Round 7
// 98.208 us; speedup vs baseline: 1.1210x; 1.0718x over previous
//
#include <hip/hip_runtime.h>

// out[r][c] = (float)weight[r][c] * scale[r]
// weight: int32 container holding int8 values, shape (8192, 8192)
// scale:  f32, shape (8192, 1)
// out:    f32, shape (8192, 8192)
//
// Memory-bound streaming: 256 MB read + 256 MB write, zero reuse.
// History:
//  R1 simple grid-stride x4 vec          : 109.4 us (4.9 TB/s)
//  R2 grid-stride 4x unroll + nt         : 116.3 us (REGRESS)
//  R3 block-interleaved 16KB chunks, x4  :  99.8 us (5.4 TB/s)  <- best
//  R4 per-block contiguous 128KB span,x8 : 110.1 us (REGRESS)
//  R5 = R3 with UNROLL 8                 : 105.3 us (REGRESS; optimum is U4)
//  R6 = R3 + single change: EXACT-COVER launch -- one block per 16KB chunk
//       (16384 blocks, no grid-stride loop). HW dispatcher pipelines block
//       launch/retire; removes end-of-sweep imbalance; sweep order preserved.

typedef int   iv4 __attribute__((ext_vector_type(4)));
typedef float fv4 __attribute__((ext_vector_type(4)));

#define BLOCK 256
#define UNROLL 4
#define CHUNK (BLOCK * UNROLL)   // 4-wide groups per block (= 16 KB)

__global__ __launch_bounds__(BLOCK) void decompress_int8_sym_kernel(
    const iv4* __restrict__ w4,
    const float* __restrict__ scale,
    fv4* __restrict__ out4,
    int n4,           // total 4-wide groups = OUT*IN/4
    int row_shift)    // log2(IN/4)
{
    const int tid = threadIdx.x;
    const int base = blockIdx.x * CHUNK;

    if (base + CHUNK <= n4) {
        int idx[UNROLL];
        iv4 v[UNROLL];
        float s[UNROLL];
#pragma unroll
        for (int u = 0; u < UNROLL; ++u) {
            idx[u] = base + u * BLOCK + tid;
            v[u] = w4[idx[u]];
        }
#pragma unroll
        for (int u = 0; u < UNROLL; ++u)
            s[u] = scale[idx[u] >> row_shift];
#pragma unroll
        for (int u = 0; u < UNROLL; ++u) {
            fv4 o;
            o.x = (float)v[u].x * s[u];
            o.y = (float)v[u].y * s[u];
            o.z = (float)v[u].z * s[u];
            o.w = (float)v[u].w * s[u];
            out4[idx[u]] = o;
        }
    } else {
        // Partial last chunk
        for (int i = base + tid; i < n4; i += BLOCK) {
            iv4 v = w4[i];
            float s = scale[i >> row_shift];
            fv4 o;
            o.x = (float)v.x * s;
            o.y = (float)v.y * s;
            o.z = (float)v.z * s;
            o.w = (float)v.w * s;
            out4[i] = o;
        }
    }
}

extern "C" void kernel_launch(void* const* d_in, const int* in_sizes, int n_in,
                              void* d_out, int out_size, void* d_ws, size_t ws_size,
                              hipStream_t stream) {
    const iv4* w4 = (const iv4*)d_in[0];         // int32 weights, vectorized x4
    const float* scale = (const float*)d_in[1];  // per-row scales
    fv4* out4 = (fv4*)d_out;

    const int n_weights = in_sizes[0];           // OUT * IN
    const int n_rows    = in_sizes[1];           // OUT
    const int in_per_row = n_weights / n_rows;   // IN
    const int groups_per_row = in_per_row / 4;   // IN/4 (power of two here)
    const int row_shift = __builtin_ctz(groups_per_row);
    const int n4 = n_weights / 4;

    const int grid = (n4 + CHUNK - 1) / CHUNK;   // exact cover: 1 block per chunk

    decompress_int8_sym_kernel<<<grid, BLOCK, 0, stream>>>(w4, scale, out4, n4, row_shift);
}

// Round 8
// 81.258 us; speedup vs baseline: 1.3548x; 1.2086x over previous
//
#include <hip/hip_runtime.h>

// out[r][c] = (float)weight[r][c] * scale[r]
// weight: int32 container holding int8 values, shape (8192, 8192)
// scale:  f32, shape (8192, 1)
// out:    f32, shape (8192, 8192)
//
// Memory-bound streaming: 256 MB read + 256 MB write, zero reuse.
// History:
//  R1 simple grid-stride x4 vec          : 109.4 us (4.9 TB/s)
//  R2 grid-stride 4x unroll + nt both    : 116.3 us (REGRESS, confounded)
//  R3 block-interleaved 16KB chunks, x4  :  99.8 us (5.4 TB/s)
//  R4 per-block contiguous 128KB span,x8 : 110.1 us (REGRESS)
//  R5 = R3 with UNROLL 8                 : 105.3 us (REGRESS; optimum U4)
//  R6 = R3 + exact-cover launch          :  98.2 us (5.47 TB/s) <- best
//  R7 = R6 + single change: NON-TEMPORAL STORES only. Output stream is never
//       re-read; nt store bypasses L2/L3 retention so caches serve only the
//       read stream. Loads remain plain (cached).

typedef int   iv4 __attribute__((ext_vector_type(4)));
typedef float fv4 __attribute__((ext_vector_type(4)));

#define BLOCK 256
#define UNROLL 4
#define CHUNK (BLOCK * UNROLL)   // 4-wide groups per block (= 16 KB)

__global__ __launch_bounds__(BLOCK) void decompress_int8_sym_kernel(
    const iv4* __restrict__ w4,
    const float* __restrict__ scale,
    fv4* __restrict__ out4,
    int n4,           // total 4-wide groups = OUT*IN/4
    int row_shift)    // log2(IN/4)
{
    const int tid = threadIdx.x;
    const int base = blockIdx.x * CHUNK;

    if (base + CHUNK <= n4) {
        int idx[UNROLL];
        iv4 v[UNROLL];
        float s[UNROLL];
#pragma unroll
        for (int u = 0; u < UNROLL; ++u) {
            idx[u] = base + u * BLOCK + tid;
            v[u] = w4[idx[u]];
        }
#pragma unroll
        for (int u = 0; u < UNROLL; ++u)
            s[u] = scale[idx[u] >> row_shift];
#pragma unroll
        for (int u = 0; u < UNROLL; ++u) {
            fv4 o;
            o.x = (float)v[u].x * s[u];
            o.y = (float)v[u].y * s[u];
            o.z = (float)v[u].z * s[u];
            o.w = (float)v[u].w * s[u];
            __builtin_nontemporal_store(o, &out4[idx[u]]);
        }
    } else {
        // Partial last chunk
        for (int i = base + tid; i < n4; i += BLOCK) {
            iv4 v = w4[i];
            float s = scale[i >> row_shift];
            fv4 o;
            o.x = (float)v.x * s;
            o.y = (float)v.y * s;
            o.z = (float)v.z * s;
            o.w = (float)v.w * s;
            __builtin_nontemporal_store(o, &out4[i]);
        }
    }
}

extern "C" void kernel_launch(void* const* d_in, const int* in_sizes, int n_in,
                              void* d_out, int out_size, void* d_ws, size_t ws_size,
                              hipStream_t stream) {
    const iv4* w4 = (const iv4*)d_in[0];         // int32 weights, vectorized x4
    const float* scale = (const float*)d_in[1];  // per-row scales
    fv4* out4 = (fv4*)d_out;

    const int n_weights = in_sizes[0];           // OUT * IN
    const int n_rows    = in_sizes[1];           // OUT
    const int in_per_row = n_weights / n_rows;   // IN
    const int groups_per_row = in_per_row / 4;   // IN/4 (power of two here)
    const int row_shift = __builtin_ctz(groups_per_row);
    const int n4 = n_weights / 4;

    const int grid = (n4 + CHUNK - 1) / CHUNK;   // exact cover: 1 block per chunk

    decompress_int8_sym_kernel<<<grid, BLOCK, 0, stream>>>(w4, scale, out4, n4, row_shift);
}